// Round 2
// baseline (285.270 us; speedup 1.0000x reference)
//
#include <hip/hip_runtime.h>
#include <hip/hip_bf16.h>

// ---------------------------------------------------------------------------
// Equivariant conv block. MFMA 32x32x16 implicit GEMM, 2x2 reg tiles/wave.
//   C_in folded: 16 (s) + 48 (v) + 96 (t-sym) = 160; chunk-major layouts.
// R9 = R8 + (a) BALANCED flat K-split, (b) coalesced two-pass LDS-transpose
// epilogue with bf16 partials, (c) combine reads bf16 partials, (d) merged prep.
// R11 = R9 + T1 XCD-aware bijective blockIdx swizzle on conv grid (1024%8==0):
// groups the 8 same-ks spatial-neighbor blocks (identical wl reads, overlapping
// xt rows) + their 16 ks-splits onto one XCD -> per-XCD L2 reuse instead of
// 8x duplicate LLC fetches. Correctness-invariant (pure block remap).
// ---------------------------------------------------------------------------

using f4  = __attribute__((ext_vector_type(4)))  float;
using f16v= __attribute__((ext_vector_type(16))) float;
using s8  = __attribute__((ext_vector_type(8)))  short;  // 8 bf16

#define C_TOT 160
#define PZ_   37
#define NTAP  343
#define NROW  (4 * PZ_ * PZ_)   // 5476 (b,z,y) rows per chunk
#define KSN   16
#define NT5   490               // 10 chunks * 49 zy
#define SLICE_E 1048576         // bf16 elems per partial slice (4*64*4096)

// conv LDS: A [row16][slot38][cg2][16B], row stride 1232B (data 1216 + 16 pad).
// A staged as 20 x 1024B chunks (slack clamped). B at 20480: [kx7][nt2][cg2][n32][16B].
// Epilogue reuses [0, 33792) as yb[64n][33 f4] (padded).
#define AROW    1232
#define B_OFF   20480
#define LDS_SZ  (B_OFF + 14336)    // 34816 (x4 blocks = 139264 <= 160KB)

__device__ __forceinline__ void gl_lds16(const void* g, void* l) {
    __builtin_amdgcn_global_load_lds(
        (const __attribute__((address_space(1))) unsigned int*)g,
        (__attribute__((address_space(3))) unsigned int*)l, 16, 0, 0);
}

__device__ __forceinline__ void pair_ij(int p, int& i, int& j) {
    if (p < 3)      { i = p; j = p; }
    else if (p == 3){ i = 0; j = 1; }
    else if (p == 4){ i = 0; j = 2; }
    else            { i = 1; j = 2; }
}

struct bf2 { __hip_bfloat16 x, y; };
struct bh4 { __hip_bfloat16 x, y, z, w; };

// ---------------------------------------------------------------------------
// Merged prep: bid < 1372 -> build_w (tap = bid>>2, j-quarter), else build_xt.
// xt[chunk][brow][s][16ch], brow=(b*37+z)*37+y.  wl[chunk][tap][n][16ch].
// ---------------------------------------------------------------------------
__global__ void prep_kernel(
    const float* __restrict__ sv,
    const float* __restrict__ b_ss, const float* __restrict__ w_ss,
    const float* __restrict__ b_sv, const float* __restrict__ w_sv,
    const float* __restrict__ b_st, const float* __restrict__ w_st,
    const float* __restrict__ b_vs, const float* __restrict__ w_vs,
    const float* __restrict__ b_vv, const float* __restrict__ w_vv,
    const float* __restrict__ b_vt, const float* __restrict__ w_vt,
    __hip_bfloat16* __restrict__ xt, __hip_bfloat16* __restrict__ wl)
{
    __shared__ float S[13056];
    const int tid = threadIdx.x;

    if (blockIdx.x < 1372) {
        // ---------------- build_w ----------------
        float* L = S;           // 750
        float* W = S + 768;     // 12288
        const int tap = blockIdx.x >> 2;
        const int jq  = (blockIdx.x & 3) * 10;
        for (int r = tid; r < 750; r += 256) {
            float v;
            if (r < 3)        v = b_ss[r * NTAP + tap];
            else if (r < 12)  v = b_sv[(r - 3) * NTAP + tap];
            else if (r < 93)  v = b_st[(r - 12) * NTAP + tap];
            else if (r < 102) v = b_vs[(r - 93) * NTAP + tap];
            else if (r < 183) v = b_vv[(r - 102) * NTAP + tap];
            else              v = b_vt[(r - 183) * NTAP + tap];
            L[r] = v;
        }
        for (int r = tid; r < 12288; r += 256) {
            float v;
            if (r < 768)       v = w_ss[r];
            else if (r < 1536) v = w_sv[r - 768];
            else if (r < 3840) v = w_st[r - 1536];
            else if (r < 4608) v = w_vs[r - 3840];
            else if (r < 6912) v = w_vv[r - 4608];
            else               v = w_vt[r - 6912];
            W[r] = v;
        }
        __syncthreads();
        for (int j = jq; j < jq + 10; ++j) {
            const int idx = j * 256 + tid;
            const int c = idx % C_TOT, n = idx / C_TOT;
            float acc = 0.f;
            if (n < 16) {
                const int u = n;
                if (c < 16) {
                    for (int t = 0; t < 3; ++t) acc += W[(u*16 + c)*3 + t] * L[t];
                } else if (c < 64) {
                    int mm = (c-16)/3, di = (c-16)%3;
                    for (int t = 0; t < 3; ++t)
                        acc += W[768 + (u*16+mm)*3 + t] * L[3 + t*3 + di];
                } else {
                    int q = c-64, mm = q/6, p = q%6, i, jj;
                    pair_ij(p, i, jj);
                    int d1 = i*3+jj, d2 = jj*3+i;
                    for (int t = 0; t < 9; ++t) {
                        float bs = L[12 + t*9 + d1];
                        if (i != jj) bs += L[12 + t*9 + d2];
                        acc += W[1536 + (u*16+mm)*9 + t] * bs;
                    }
                }
            } else {
                const int u = (n-16)/3, dn = (n-16)%3;
                if (c < 16) {
                    for (int t = 0; t < 3; ++t)
                        acc += W[3840 + (u*16+c)*3 + t] * L[93 + t*3 + dn];
                } else if (c < 64) {
                    int mm = (c-16)/3, di = (c-16)%3;
                    for (int t = 0; t < 9; ++t)
                        acc += W[4608 + (u*16+mm)*9 + t] * L[102 + (t*3+dn)*3 + di];
                } else {
                    int q = c-64, mm = q/6, p = q%6, i, jj;
                    pair_ij(p, i, jj);
                    int d1 = i*3+jj, d2 = jj*3+i;
                    for (int t = 0; t < 21; ++t) {
                        float bs = L[183 + (t*3+dn)*9 + d1];
                        if (i != jj) bs += L[183 + (t*3+dn)*9 + d2];
                        acc += W[6912 + (u*16+mm)*21 + t] * bs;
                    }
                }
            }
            const int chunk = c >> 4, cw = c & 15;
            wl[((size_t)chunk * NTAP + tap) * 1024 + (size_t)n * 16 + cw] =
                __float2bfloat16(acc);
        }
    } else {
        // ---------------- build_xt ----------------
        float* row = S;                              // 32*66 = 2112
        const int bid = blockIdx.x - 1372;           // (b*37 + z)*37 + y
        const int y = bid % 37, z = (bid / 37) % 37, b = bid / 1369;
        const bool interior = (z >= 3 && z < 35 && y >= 3 && y < 35);
        if (interior) {
            const float* src = sv + (size_t)b * 2097152 + (z-3) * 1024 + (y-3) * 32;
            for (int f = tid; f < 2048; f += 256) {
                int ch = f >> 5, x = f & 31;
                row[x * 66 + ch] = src[(size_t)ch * 32768 + x];
            }
        }
        __syncthreads();
        for (int e2 = tid; e2 < 38 * 80; e2 += 256) {
            const int s = e2 / 80, cp = e2 % 80, c = cp * 2;
            float v0 = 0.f, v1 = 0.f;
            if (interior && s >= 3 && s < 35) {
                const int x = s - 3;
                if (c < 64) {
                    v0 = row[x * 66 + c];
                    v1 = row[x * 66 + c + 1];
                } else {
                    int q = c - 64, u = q / 6, p = q % 6, i, j;
                    pair_ij(p, i, j);
                    v0 = row[x * 66 + 16 + u * 3 + i] * row[x * 66 + 16 + u * 3 + j];
                    pair_ij(p + 1, i, j);
                    v1 = row[x * 66 + 16 + u * 3 + i] * row[x * 66 + 16 + u * 3 + j];
                }
            }
            bf2 w{__float2bfloat16(v0), __float2bfloat16(v1)};
            const int chunk = c >> 4, cw = c & 15;
            *(bf2*)(xt + ((size_t)chunk * NROW + bid) * 608 + s * 16 + cw) = w;
        }
    }
}

// ---------------------------------------------------------------------------
// Conv. Grid 64*KSN. Logical bid = (mb>>3)*(8*KSN) + ks*8 + (mb&3 bits).
// R11: physical->logical XCD swizzle (bijective, 1024%8==0): phys round-robin
// across XCDs means phys%8 = XCD id; logical id (phys%8)*128 + phys/8 gives
// each XCD a contiguous run of 128 logical blocks = all 16 ks-splits of one
// mb-octet (same-ks octet shares wl exactly + xt spatially).
// BALANCED flat K-split: t = ks..489 step 16. Hoisted staging.
// Epilogue: two-pass LDS transpose -> coalesced bf16 partial stores.
// ---------------------------------------------------------------------------
__global__ __launch_bounds__(256, 4) void conv_mfma_kernel(
    const __hip_bfloat16* __restrict__ xt,
    const __hip_bfloat16* __restrict__ wl,
    __hip_bfloat16* __restrict__ y4b)
{
    __shared__ __align__(16) char lds[LDS_SZ];

    // T1 XCD swizzle: grid = 1024 = 8 XCDs x 128.
    const int phys = blockIdx.x;
    const int bid  = (phys & 7) * (64 * KSN / 8) + (phys >> 3);

    const int low3 = bid & 7;
    const int rest = bid >> 3;
    const int ks   = rest % KSN;
    const int mb   = (rest / KSN) * 8 + low3;
    const int b    = mb >> 4;
    const int oz0 = ((mb >> 2) & 3) * 4;
    const int oy0 = (mb & 3) * 4;

    const int tid  = threadIdx.x;
    const int w    = tid >> 6;          // x-quarter
    const int lane = tid & 63;
    const int m    = lane & 31;
    const int h    = lane >> 5;         // k-half (8-ch group)

    // ---- per-lane invariant staging offsets (elements) + LDS dsts ----
    int  invA[5];  char* dstA[5];
#pragma unroll
    for (int k = 0; k < 5; ++k) {
        const int i = w + 4 * k;                 // < 20 always
        const int o = i * 1024 + lane * 16;
        int r = o / AROW;
        int rem = o - r * AROW;
        if (r > 15) { r = 15; rem = 0; }         // slack: dummy src
        if (rem >= 1216) rem = 0;                // row pad: dummy src
        const int s  = rem >> 5;
        const int cg = ((rem >> 4) & 1) ^ ((s >> 1) & 1);
        const int base_row = (b * PZ_ + 2 * (oz0 + (r >> 2))) * PZ_
                           + 2 * (oy0 + (r & 3));
        invA[k] = base_row * 608 + s * 16 + cg * 8;
        dstA[k] = lds + i * 1024;
    }
    int  invB[4];  char* dstB[4];  int nB = 0;
#pragma unroll
    for (int k = 0; k < 4; ++k) {
        const int i = w + 4 * k;
        if (i < 14) {
            const int kx = i >> 1, nt = i & 1;
            invB[k] = kx * 1024 + (nt * 32 + m) * 16 + h * 8;
            dstB[k] = lds + B_OFF + i * 1024;
            nB = k + 1;
        }
    }

    f16v acc[2][2];
    for (int t = 0; t < 2; ++t)
        for (int n = 0; n < 2; ++n)
            for (int k = 0; k < 16; ++k) acc[t][n][k] = 0.f;

    const int rA0   = ((m >> 4) << 2) + ((m >> 2) & 3);   // LDS row for t=0
    const int sbase = (w << 3) + ((m & 3) << 1);          // + kx -> x slot

    for (int t5 = ks; t5 < NT5; t5 += KSN) {
        const int chunk = t5 / 49;
        const int zy    = t5 - chunk * 49;
        const int kz = zy / 7, ky = zy - kz * 7;
        const int u_a = (chunk * NROW + kz * PZ_ + ky) * 608;   // uniform
        const int u_b = (chunk * NTAP + zy * 7) * 1024;         // uniform
        __syncthreads();

#pragma unroll
        for (int k = 0; k < 5; ++k)
            gl_lds16(xt + u_a + invA[k], dstA[k]);
#pragma unroll
        for (int k = 0; k < 4; ++k)
            if (k < nB) gl_lds16(wl + u_b + invB[k], dstB[k]);
        __syncthreads();                           // drains lds-DMA

#pragma unroll
        for (int kx = 0; kx < 7; ++kx) {
            const int s   = sbase + kx;
            const int cgp = h ^ ((s >> 1) & 1);
            const char* ap = lds + rA0 * AROW + s * 32 + cgp * 16;
            const s8 a0 = *(const s8*)(ap);
            const s8 a1 = *(const s8*)(ap + 8 * AROW);
            const char* bp = lds + B_OFF + kx * 2048 + h * 512 + m * 16;
            const s8 b0 = *(const s8*)(bp);
            const s8 b1 = *(const s8*)(bp + 1024);
            acc[0][0] = __builtin_amdgcn_mfma_f32_32x32x16_bf16(a0, b0, acc[0][0], 0, 0, 0);
            acc[0][1] = __builtin_amdgcn_mfma_f32_32x32x16_bf16(a0, b1, acc[0][1], 0, 0, 0);
            acc[1][0] = __builtin_amdgcn_mfma_f32_32x32x16_bf16(a1, b0, acc[1][0], 0, 0, 0);
            acc[1][1] = __builtin_amdgcn_mfma_f32_32x32x16_bf16(a1, b1, acc[1][1], 0, 0, 0);
        }
    }

    // ---- epilogue: two-pass LDS transpose, coalesced bf16 partial stores ----
    // C/D 32x32: col(n)=lane&31, row m32=(reg&3)+8*(reg>>2)+4*h  [m74/m101]
    const int nl = lane & 31;
    f4* yb = (f4*)lds;                  // [64n][33 f4] padded = 33792 B
    __hip_bfloat16* dst0 = y4b + (size_t)ks * SLICE_E + (size_t)(b * 64) * 4096;
#pragma unroll
    for (int t = 0; t < 2; ++t) {       // mz-half
        __syncthreads();                // prior readers (or compute) done
#pragma unroll
        for (int nt = 0; nt < 2; ++nt) {
            const int n = nt * 32 + nl;
#pragma unroll
            for (int q = 0; q < 4; ++q) {
                const int rr = 2 * q + h;          // spatial f4 = rr*4 + w
                f4 v = { acc[t][nt][4*q], acc[t][nt][4*q+1],
                         acc[t][nt][4*q+2], acc[t][nt][4*q+3] };
                yb[n * 33 + rr * 4 + w] = v;
            }
        }
        __syncthreads();
        for (int j = tid; j < 2048; j += 256) {
            const int n  = j >> 5, sp = j & 31;    // sp = rr*4 + wq
            f4 v = yb[n * 33 + sp];
            const int rr = sp >> 2, wq = sp & 3;
            const int my = rr & 3, mz = t * 2 + (rr >> 2);
            bh4 p{__float2bfloat16(v.x), __float2bfloat16(v.y),
                  __float2bfloat16(v.z), __float2bfloat16(v.w)};
            *(bh4*)(dst0 + (size_t)n * 4096 +
                    (oz0 + mz) * 256 + (oy0 + my) * 16 + wq * 4) = p;
        }
    }
}

// ---------------------------------------------------------------------------
// Combine KSN bf16 partials -> f32 yc + per-(n,b) sum of squares. 256 blocks.
// ---------------------------------------------------------------------------
__global__ void combine_reduce_kernel(const __hip_bfloat16* __restrict__ y4b,
                                      float* __restrict__ yc,
                                      float* __restrict__ sums2)
{
    const int n = blockIdx.x & 63, q = blockIdx.x >> 6;
    const size_t base = ((size_t)q * 64 + n) * 4096;
    float s = 0.f;
    for (int i = threadIdx.x; i < 1024; i += 256) {
        const size_t off = base + (size_t)i * 4;
        f4 v = {0.f, 0.f, 0.f, 0.f};
#pragma unroll
        for (int k = 0; k < KSN; ++k) {
            bh4 r = *(const bh4*)(y4b + off + (size_t)k * SLICE_E);
            v.x += (float)r.x; v.y += (float)r.y;
            v.z += (float)r.z; v.w += (float)r.w;
        }
        *(f4*)(yc + off) = v;
        s += v.x * v.x + v.y * v.y + v.z * v.z + v.w * v.w;
    }
    __shared__ float red[256];
    red[threadIdx.x] = s;
    __syncthreads();
    for (int st = 128; st > 0; st >>= 1) {
        if (threadIdx.x < st) red[threadIdx.x] += red[threadIdx.x + st];
        __syncthreads();
    }
    if (threadIdx.x == 0) sums2[n * 4 + q] = red[0];
}

// ---------------------------------------------------------------------------
__global__ void finalize_kernel(const float* __restrict__ yc,
                                const float* __restrict__ sums2,
                                const float* __restrict__ g_s,
                                const float* __restrict__ g_v,
                                const float* __restrict__ bias_s,
                                float* __restrict__ out)
{
    const int idx = blockIdx.x * 256 + threadIdx.x;   // exact grid, 1M
    const int n = (idx >> 12) & 63;
    float v = yc[idx];
    if (n < 16) {
        float sum = sums2[n*4] + sums2[n*4+1] + sums2[n*4+2] + sums2[n*4+3];
        float var = sum * (1.0f / 16384.0f);
        float sc  = g_s[n] / sqrtf(var + 1e-5f);
        v = fmaxf(v * sc + bias_s[n], 0.f);
    } else {
        int u = (n - 16) / 3;
        float sum = 0.f;
        for (int k = 0; k < 12; ++k) sum += sums2[(16 + u * 3) * 4 + k];
        float var = sum * (1.0f / 49152.0f);
        v = v * (g_v[u] / sqrtf(var + 1e-5f));
    }
    out[idx] = v;
}

// ---------------------------------------------------------------------------
extern "C" void kernel_launch(void* const* d_in, const int* in_sizes, int n_in,
                              void* d_out, int out_size, void* d_ws, size_t ws_size,
                              hipStream_t stream)
{
    const float* sv    = (const float*)d_in[0];
    const float* b_ss  = (const float*)d_in[1];
    const float* w_ss  = (const float*)d_in[2];
    const float* b_sv  = (const float*)d_in[3];
    const float* w_sv  = (const float*)d_in[4];
    const float* b_st  = (const float*)d_in[5];
    const float* w_st  = (const float*)d_in[6];
    const float* b_vs  = (const float*)d_in[7];
    const float* w_vs  = (const float*)d_in[8];
    const float* b_vv  = (const float*)d_in[9];
    const float* w_vv  = (const float*)d_in[10];
    const float* b_vt  = (const float*)d_in[11];
    const float* w_vt  = (const float*)d_in[12];
    const float* bn_gs = (const float*)d_in[13];
    const float* bn_gv = (const float*)d_in[14];
    const float* bias_s= (const float*)d_in[15];
    float* out = (float*)d_out;

    char* ws = (char*)d_ws;
    constexpr size_t XT_BYTES = (size_t)10 * NROW * 1216;      // 66,588,160
    constexpr size_t WL_BYTES = (size_t)10 * NTAP * 2048;      //  7,024,640
    constexpr size_t Y4_BYTES = (size_t)KSN * SLICE_E * 2;     // 33,554,432
    constexpr size_t YC_BYTES = (size_t)4 * 64 * 4096 * 4;     //  4,194,304

    __hip_bfloat16* xt  = (__hip_bfloat16*)ws;
    __hip_bfloat16* wl  = (__hip_bfloat16*)(ws + XT_BYTES);
    __hip_bfloat16* y4b = (__hip_bfloat16*)(ws + XT_BYTES + WL_BYTES);
    float* yc    = (float*)(ws + XT_BYTES + WL_BYTES + Y4_BYTES);
    float* sums2 = (float*)(ws + XT_BYTES + WL_BYTES + Y4_BYTES + YC_BYTES);

    prep_kernel<<<1372 + 5476, 256, 0, stream>>>(
        sv, b_ss, w_ss, b_sv, w_sv, b_st, w_st, b_vs, w_vs, b_vv, w_vv,
        b_vt, w_vt, xt, wl);
    conv_mfma_kernel<<<64 * KSN, 256, 0, stream>>>(xt, wl, y4b);
    combine_reduce_kernel<<<256, 256, 0, stream>>>(y4b, yc, sums2);
    finalize_kernel<<<4096, 256, 0, stream>>>(yc, sums2, bn_gs, bn_gv, bias_s, out);
}

// Round 3
// 275.655 us; speedup vs baseline: 1.0349x; 1.0349x over previous
//
#include <hip/hip_runtime.h>
#include <hip/hip_bf16.h>

// ---------------------------------------------------------------------------
// Equivariant conv block. MFMA 32x32x16 implicit GEMM, 2x2 reg tiles/wave.
//   C_in folded: 16 (s) + 48 (v) + 96 (t-sym) = 160; chunk-major layouts.
// R11 = XCD swizzle (kept). Counters showed conv latency-bound: true MFMA
// ~10% of peak, HBM 13%, VALU 11% -> barrier-drain serialization.
// R12 = T3 2-phase prefetch: double-buffered LDS (2x34816=69632B), stage tile
// t+1 into other buffer BEFORE computing tile t, ONE barrier per iter (was 2),
// vmcnt(0) drain hidden under 28 ds_read + 28 MFMA. KSN 16->8 so grid=512 =
// exactly 2 blocks/CU resident (single occupancy wave) and y4b partials halve.
// ---------------------------------------------------------------------------

using f4  = __attribute__((ext_vector_type(4)))  float;
using f16v= __attribute__((ext_vector_type(16))) float;
using s8  = __attribute__((ext_vector_type(8)))  short;  // 8 bf16

#define C_TOT 160
#define PZ_   37
#define NTAP  343
#define NROW  (4 * PZ_ * PZ_)   // 5476 (b,z,y) rows per chunk
#define KSN   8
#define NT5   490               // 10 chunks * 49 zy
#define SLICE_E 1048576         // bf16 elems per partial slice (4*64*4096)

// conv LDS: A [row16][slot38][cg2][16B], row stride 1232B (data 1216 + 16 pad).
// A staged as 20 x 1024B chunks (slack clamped). B at 20480: [kx7][nt2][cg2][n32][16B].
// Double-buffered: buffer stride 34816. Epilogue reuses [0, 33792) as yb[64n][33 f4].
#define AROW    1232
#define B_OFF   20480
#define BUFSZ   34816
#define LDS_SZ  (2 * BUFSZ)        // 69632 (x2 blocks/CU = 139264 <= 160KB)

__device__ __forceinline__ void gl_lds16(const void* g, void* l) {
    __builtin_amdgcn_global_load_lds(
        (const __attribute__((address_space(1))) unsigned int*)g,
        (__attribute__((address_space(3))) unsigned int*)l, 16, 0, 0);
}

__device__ __forceinline__ void pair_ij(int p, int& i, int& j) {
    if (p < 3)      { i = p; j = p; }
    else if (p == 3){ i = 0; j = 1; }
    else if (p == 4){ i = 0; j = 2; }
    else            { i = 1; j = 2; }
}

struct bf2 { __hip_bfloat16 x, y; };
struct bh4 { __hip_bfloat16 x, y, z, w; };

// ---------------------------------------------------------------------------
// Merged prep: bid < 1372 -> build_w (tap = bid>>2, j-quarter), else build_xt.
// xt[chunk][brow][s][16ch], brow=(b*37+z)*37+y.  wl[chunk][tap][n][16ch].
// ---------------------------------------------------------------------------
__global__ void prep_kernel(
    const float* __restrict__ sv,
    const float* __restrict__ b_ss, const float* __restrict__ w_ss,
    const float* __restrict__ b_sv, const float* __restrict__ w_sv,
    const float* __restrict__ b_st, const float* __restrict__ w_st,
    const float* __restrict__ b_vs, const float* __restrict__ w_vs,
    const float* __restrict__ b_vv, const float* __restrict__ w_vv,
    const float* __restrict__ b_vt, const float* __restrict__ w_vt,
    __hip_bfloat16* __restrict__ xt, __hip_bfloat16* __restrict__ wl)
{
    __shared__ float S[13056];
    const int tid = threadIdx.x;

    if (blockIdx.x < 1372) {
        // ---------------- build_w ----------------
        float* L = S;           // 750
        float* W = S + 768;     // 12288
        const int tap = blockIdx.x >> 2;
        const int jq  = (blockIdx.x & 3) * 10;
        for (int r = tid; r < 750; r += 256) {
            float v;
            if (r < 3)        v = b_ss[r * NTAP + tap];
            else if (r < 12)  v = b_sv[(r - 3) * NTAP + tap];
            else if (r < 93)  v = b_st[(r - 12) * NTAP + tap];
            else if (r < 102) v = b_vs[(r - 93) * NTAP + tap];
            else if (r < 183) v = b_vv[(r - 102) * NTAP + tap];
            else              v = b_vt[(r - 183) * NTAP + tap];
            L[r] = v;
        }
        for (int r = tid; r < 12288; r += 256) {
            float v;
            if (r < 768)       v = w_ss[r];
            else if (r < 1536) v = w_sv[r - 768];
            else if (r < 3840) v = w_st[r - 1536];
            else if (r < 4608) v = w_vs[r - 3840];
            else if (r < 6912) v = w_vv[r - 4608];
            else               v = w_vt[r - 6912];
            W[r] = v;
        }
        __syncthreads();
        for (int j = jq; j < jq + 10; ++j) {
            const int idx = j * 256 + tid;
            const int c = idx % C_TOT, n = idx / C_TOT;
            float acc = 0.f;
            if (n < 16) {
                const int u = n;
                if (c < 16) {
                    for (int t = 0; t < 3; ++t) acc += W[(u*16 + c)*3 + t] * L[t];
                } else if (c < 64) {
                    int mm = (c-16)/3, di = (c-16)%3;
                    for (int t = 0; t < 3; ++t)
                        acc += W[768 + (u*16+mm)*3 + t] * L[3 + t*3 + di];
                } else {
                    int q = c-64, mm = q/6, p = q%6, i, jj;
                    pair_ij(p, i, jj);
                    int d1 = i*3+jj, d2 = jj*3+i;
                    for (int t = 0; t < 9; ++t) {
                        float bs = L[12 + t*9 + d1];
                        if (i != jj) bs += L[12 + t*9 + d2];
                        acc += W[1536 + (u*16+mm)*9 + t] * bs;
                    }
                }
            } else {
                const int u = (n-16)/3, dn = (n-16)%3;
                if (c < 16) {
                    for (int t = 0; t < 3; ++t)
                        acc += W[3840 + (u*16+c)*3 + t] * L[93 + t*3 + dn];
                } else if (c < 64) {
                    int mm = (c-16)/3, di = (c-16)%3;
                    for (int t = 0; t < 9; ++t)
                        acc += W[4608 + (u*16+mm)*9 + t] * L[102 + (t*3+dn)*3 + di];
                } else {
                    int q = c-64, mm = q/6, p = q%6, i, jj;
                    pair_ij(p, i, jj);
                    int d1 = i*3+jj, d2 = jj*3+i;
                    for (int t = 0; t < 21; ++t) {
                        float bs = L[183 + (t*3+dn)*9 + d1];
                        if (i != jj) bs += L[183 + (t*3+dn)*9 + d2];
                        acc += W[6912 + (u*16+mm)*21 + t] * bs;
                    }
                }
            }
            const int chunk = c >> 4, cw = c & 15;
            wl[((size_t)chunk * NTAP + tap) * 1024 + (size_t)n * 16 + cw] =
                __float2bfloat16(acc);
        }
    } else {
        // ---------------- build_xt ----------------
        float* row = S;                              // 32*66 = 2112
        const int bid = blockIdx.x - 1372;           // (b*37 + z)*37 + y
        const int y = bid % 37, z = (bid / 37) % 37, b = bid / 1369;
        const bool interior = (z >= 3 && z < 35 && y >= 3 && y < 35);
        if (interior) {
            const float* src = sv + (size_t)b * 2097152 + (z-3) * 1024 + (y-3) * 32;
            for (int f = tid; f < 2048; f += 256) {
                int ch = f >> 5, x = f & 31;
                row[x * 66 + ch] = src[(size_t)ch * 32768 + x];
            }
        }
        __syncthreads();
        for (int e2 = tid; e2 < 38 * 80; e2 += 256) {
            const int s = e2 / 80, cp = e2 % 80, c = cp * 2;
            float v0 = 0.f, v1 = 0.f;
            if (interior && s >= 3 && s < 35) {
                const int x = s - 3;
                if (c < 64) {
                    v0 = row[x * 66 + c];
                    v1 = row[x * 66 + c + 1];
                } else {
                    int q = c - 64, u = q / 6, p = q % 6, i, j;
                    pair_ij(p, i, j);
                    v0 = row[x * 66 + 16 + u * 3 + i] * row[x * 66 + 16 + u * 3 + j];
                    pair_ij(p + 1, i, j);
                    v1 = row[x * 66 + 16 + u * 3 + i] * row[x * 66 + 16 + u * 3 + j];
                }
            }
            bf2 w{__float2bfloat16(v0), __float2bfloat16(v1)};
            const int chunk = c >> 4, cw = c & 15;
            *(bf2*)(xt + ((size_t)chunk * NROW + bid) * 608 + s * 16 + cw) = w;
        }
    }
}

// ---------------------------------------------------------------------------
// Conv. Grid 64*KSN = 512 (exactly 2 blocks/CU resident, one occupancy wave).
// XCD swizzle (bijective, 512%8==0). 2-phase prefetch: stage t+1 into the
// other LDS buffer before computing t; one __syncthreads per iter drains
// vmcnt(0) AFTER compute (latency hidden). BALANCED flat K-split t=ks..489
// step 8 (62/61 iters). Epilogue: two-pass LDS transpose, bf16 partials.
// ---------------------------------------------------------------------------
__global__ __launch_bounds__(256, 2) void conv_mfma_kernel(
    const __hip_bfloat16* __restrict__ xt,
    const __hip_bfloat16* __restrict__ wl,
    __hip_bfloat16* __restrict__ y4b)
{
    __shared__ __align__(16) char lds[LDS_SZ];

    // T1 XCD swizzle: grid = 512 = 8 XCDs x 64.
    const int phys = blockIdx.x;
    const int bid  = (phys & 7) * (64 * KSN / 8) + (phys >> 3);

    const int low3 = bid & 7;
    const int rest = bid >> 3;
    const int ks   = rest % KSN;
    const int mb   = (rest / KSN) * 8 + low3;
    const int b    = mb >> 4;
    const int oz0 = ((mb >> 2) & 3) * 4;
    const int oy0 = (mb & 3) * 4;

    const int tid  = threadIdx.x;
    const int w    = tid >> 6;          // x-quarter
    const int lane = tid & 63;
    const int m    = lane & 31;
    const int h    = lane >> 5;         // k-half (8-ch group)

    // ---- per-lane invariant staging offsets (elements) + LDS offsets ----
    int invA[5], offA[5];
#pragma unroll
    for (int k = 0; k < 5; ++k) {
        const int i = w + 4 * k;                 // < 20 always
        const int o = i * 1024 + lane * 16;
        int r = o / AROW;
        int rem = o - r * AROW;
        if (r > 15) { r = 15; rem = 0; }         // slack: dummy src
        if (rem >= 1216) rem = 0;                // row pad: dummy src
        const int s  = rem >> 5;
        const int cg = ((rem >> 4) & 1) ^ ((s >> 1) & 1);
        const int base_row = (b * PZ_ + 2 * (oz0 + (r >> 2))) * PZ_
                           + 2 * (oy0 + (r & 3));
        invA[k] = base_row * 608 + s * 16 + cg * 8;
        offA[k] = i * 1024;
    }
    int invB[4], offB[4];  int nB = 0;
#pragma unroll
    for (int k = 0; k < 4; ++k) {
        const int i = w + 4 * k;
        if (i < 14) {
            const int kx = i >> 1, nt = i & 1;
            invB[k] = kx * 1024 + (nt * 32 + m) * 16 + h * 8;
            offB[k] = B_OFF + i * 1024;
            nB = k + 1;
        }
    }

    f16v acc[2][2];
    for (int t = 0; t < 2; ++t)
        for (int n = 0; n < 2; ++n)
            for (int k = 0; k < 16; ++k) acc[t][n][k] = 0.f;

    const int rA0   = ((m >> 4) << 2) + ((m >> 2) & 3);   // LDS row for t=0
    const int sbase = (w << 3) + ((m & 3) << 1);          // + kx -> x slot

    auto stage = [&](int t5s, int bufofs) {
        const int chunk = t5s / 49;
        const int zy    = t5s - chunk * 49;
        const int kz = zy / 7, ky = zy - kz * 7;
        const int u_a = (chunk * NROW + kz * PZ_ + ky) * 608;   // uniform
        const int u_b = (chunk * NTAP + zy * 7) * 1024;         // uniform
#pragma unroll
        for (int k = 0; k < 5; ++k)
            gl_lds16(xt + u_a + invA[k], lds + bufofs + offA[k]);
#pragma unroll
        for (int k = 0; k < 4; ++k)
            if (k < nB) gl_lds16(wl + u_b + invB[k], lds + bufofs + offB[k]);
    };

    auto compute = [&](int bufofs) {
#pragma unroll
        for (int kx = 0; kx < 7; ++kx) {
            const int s   = sbase + kx;
            const int cgp = h ^ ((s >> 1) & 1);
            const char* ap = lds + bufofs + rA0 * AROW + s * 32 + cgp * 16;
            const s8 a0 = *(const s8*)(ap);
            const s8 a1 = *(const s8*)(ap + 8 * AROW);
            const char* bp = lds + bufofs + B_OFF + kx * 2048 + h * 512 + m * 16;
            const s8 b0 = *(const s8*)(bp);
            const s8 b1 = *(const s8*)(bp + 1024);
            acc[0][0] = __builtin_amdgcn_mfma_f32_32x32x16_bf16(a0, b0, acc[0][0], 0, 0, 0);
            acc[0][1] = __builtin_amdgcn_mfma_f32_32x32x16_bf16(a0, b1, acc[0][1], 0, 0, 0);
            acc[1][0] = __builtin_amdgcn_mfma_f32_32x32x16_bf16(a1, b0, acc[1][0], 0, 0, 0);
            acc[1][1] = __builtin_amdgcn_mfma_f32_32x32x16_bf16(a1, b1, acc[1][1], 0, 0, 0);
        }
    };

    // ---- 2-phase prefetch main loop: one barrier per iteration ----
    stage(ks, 0);
    __syncthreads();                    // vmcnt(0) drain + barrier (prologue)
    int buf = 0;
    int t5  = ks;
    for (;;) {
        const int t5n = t5 + KSN;
        const bool more = (t5n < NT5);
        if (more) stage(t5n, buf ^ BUFSZ);   // issue next tile early
        compute(buf);                        // hides the staging latency
        if (!more) break;
        __syncthreads();                     // drains vmcnt(0): next tile ready
        buf ^= BUFSZ;
        t5 = t5n;
    }

    // ---- epilogue: two-pass LDS transpose, coalesced bf16 partial stores ----
    // C/D 32x32: col(n)=lane&31, row m32=(reg&3)+8*(reg>>2)+4*h  [m74/m101]
    const int nl = lane & 31;
    f4* yb = (f4*)lds;                  // [64n][33 f4] padded = 33792 B
    __hip_bfloat16* dst0 = y4b + (size_t)ks * SLICE_E + (size_t)(b * 64) * 4096;
#pragma unroll
    for (int t = 0; t < 2; ++t) {       // mz-half
        __syncthreads();                // prior readers (or compute) done
#pragma unroll
        for (int nt = 0; nt < 2; ++nt) {
            const int n = nt * 32 + nl;
#pragma unroll
            for (int q = 0; q < 4; ++q) {
                const int rr = 2 * q + h;          // spatial f4 = rr*4 + w
                f4 v = { acc[t][nt][4*q], acc[t][nt][4*q+1],
                         acc[t][nt][4*q+2], acc[t][nt][4*q+3] };
                yb[n * 33 + rr * 4 + w] = v;
            }
        }
        __syncthreads();
        for (int j = tid; j < 2048; j += 256) {
            const int n  = j >> 5, sp = j & 31;    // sp = rr*4 + wq
            f4 v = yb[n * 33 + sp];
            const int rr = sp >> 2, wq = sp & 3;
            const int my = rr & 3, mz = t * 2 + (rr >> 2);
            bh4 p{__float2bfloat16(v.x), __float2bfloat16(v.y),
                  __float2bfloat16(v.z), __float2bfloat16(v.w)};
            *(bh4*)(dst0 + (size_t)n * 4096 +
                    (oz0 + mz) * 256 + (oy0 + my) * 16 + wq * 4) = p;
        }
    }
}

// ---------------------------------------------------------------------------
// Combine KSN bf16 partials -> f32 yc + per-(n,b) sum of squares. 256 blocks.
// ---------------------------------------------------------------------------
__global__ void combine_reduce_kernel(const __hip_bfloat16* __restrict__ y4b,
                                      float* __restrict__ yc,
                                      float* __restrict__ sums2)
{
    const int n = blockIdx.x & 63, q = blockIdx.x >> 6;
    const size_t base = ((size_t)q * 64 + n) * 4096;
    float s = 0.f;
    for (int i = threadIdx.x; i < 1024; i += 256) {
        const size_t off = base + (size_t)i * 4;
        f4 v = {0.f, 0.f, 0.f, 0.f};
#pragma unroll
        for (int k = 0; k < KSN; ++k) {
            bh4 r = *(const bh4*)(y4b + off + (size_t)k * SLICE_E);
            v.x += (float)r.x; v.y += (float)r.y;
            v.z += (float)r.z; v.w += (float)r.w;
        }
        *(f4*)(yc + off) = v;
        s += v.x * v.x + v.y * v.y + v.z * v.z + v.w * v.w;
    }
    __shared__ float red[256];
    red[threadIdx.x] = s;
    __syncthreads();
    for (int st = 128; st > 0; st >>= 1) {
        if (threadIdx.x < st) red[threadIdx.x] += red[threadIdx.x + st];
        __syncthreads();
    }
    if (threadIdx.x == 0) sums2[n * 4 + q] = red[0];
}

// ---------------------------------------------------------------------------
__global__ void finalize_kernel(const float* __restrict__ yc,
                                const float* __restrict__ sums2,
                                const float* __restrict__ g_s,
                                const float* __restrict__ g_v,
                                const float* __restrict__ bias_s,
                                float* __restrict__ out)
{
    const int idx = blockIdx.x * 256 + threadIdx.x;   // exact grid, 1M
    const int n = (idx >> 12) & 63;
    float v = yc[idx];
    if (n < 16) {
        float sum = sums2[n*4] + sums2[n*4+1] + sums2[n*4+2] + sums2[n*4+3];
        float var = sum * (1.0f / 16384.0f);
        float sc  = g_s[n] / sqrtf(var + 1e-5f);
        v = fmaxf(v * sc + bias_s[n], 0.f);
    } else {
        int u = (n - 16) / 3;
        float sum = 0.f;
        for (int k = 0; k < 12; ++k) sum += sums2[(16 + u * 3) * 4 + k];
        float var = sum * (1.0f / 49152.0f);
        v = v * (g_v[u] / sqrtf(var + 1e-5f));
    }
    out[idx] = v;
}

// ---------------------------------------------------------------------------
extern "C" void kernel_launch(void* const* d_in, const int* in_sizes, int n_in,
                              void* d_out, int out_size, void* d_ws, size_t ws_size,
                              hipStream_t stream)
{
    const float* sv    = (const float*)d_in[0];
    const float* b_ss  = (const float*)d_in[1];
    const float* w_ss  = (const float*)d_in[2];
    const float* b_sv  = (const float*)d_in[3];
    const float* w_sv  = (const float*)d_in[4];
    const float* b_st  = (const float*)d_in[5];
    const float* w_st  = (const float*)d_in[6];
    const float* b_vs  = (const float*)d_in[7];
    const float* w_vs  = (const float*)d_in[8];
    const float* b_vv  = (const float*)d_in[9];
    const float* w_vv  = (const float*)d_in[10];
    const float* b_vt  = (const float*)d_in[11];
    const float* w_vt  = (const float*)d_in[12];
    const float* bn_gs = (const float*)d_in[13];
    const float* bn_gv = (const float*)d_in[14];
    const float* bias_s= (const float*)d_in[15];
    float* out = (float*)d_out;

    char* ws = (char*)d_ws;
    constexpr size_t XT_BYTES = (size_t)10 * NROW * 1216;      // 66,588,160
    constexpr size_t WL_BYTES = (size_t)10 * NTAP * 2048;      //  7,024,640
    constexpr size_t Y4_BYTES = (size_t)KSN * SLICE_E * 2;     // 16,777,216
    constexpr size_t YC_BYTES = (size_t)4 * 64 * 4096 * 4;     //  4,194,304

    __hip_bfloat16* xt  = (__hip_bfloat16*)ws;
    __hip_bfloat16* wl  = (__hip_bfloat16*)(ws + XT_BYTES);
    __hip_bfloat16* y4b = (__hip_bfloat16*)(ws + XT_BYTES + WL_BYTES);
    float* yc    = (float*)(ws + XT_BYTES + WL_BYTES + Y4_BYTES);
    float* sums2 = (float*)(ws + XT_BYTES + WL_BYTES + Y4_BYTES + YC_BYTES);

    prep_kernel<<<1372 + 5476, 256, 0, stream>>>(
        sv, b_ss, w_ss, b_sv, w_sv, b_st, w_st, b_vs, w_vs, b_vv, w_vv,
        b_vt, w_vt, xt, wl);
    conv_mfma_kernel<<<64 * KSN, 256, 0, stream>>>(xt, wl, y4b);
    combine_reduce_kernel<<<256, 256, 0, stream>>>(y4b, yc, sums2);
    finalize_kernel<<<4096, 256, 0, stream>>>(yc, sums2, bn_gs, bn_gv, bias_s, out);
}

// Round 4
// 275.446 us; speedup vs baseline: 1.0357x; 1.0008x over previous
//
#include <hip/hip_runtime.h>
#include <hip/hip_bf16.h>

// ---------------------------------------------------------------------------
// Equivariant conv block. MFMA 32x32x16 implicit GEMM.
// R13: conv is staged-byte-bound at ~10 TB/s LLC service (R12 evidence: dur
// invariant across block/iter restructure; staged/dur = 10 TB/s; FETCH drop
// had no effect). Lever = fewer staged bytes. Retile: 1 z-out x 16 y-out x
// 16 x-out per block; per (chunk,kz) group stage the full 37-row A-stripe
// ONCE (45 KB) and loop ky against it. Tap ky reads only rows of parity ky&1
// -> A split even/odd halves, ping-pong staged across group phases (odd taps
// first, then even; next group's odd half staged during even phase) -> A
// staging fully pipelined, zero extra LDS. A staged: 625->201 MB (exact
// footprint). B unchanged (439 MB). LDS 74.75 KB/block -> 2 blocks/CU.
// ---------------------------------------------------------------------------

using f4  = __attribute__((ext_vector_type(4)))  float;
using f16v= __attribute__((ext_vector_type(16))) float;
using s8  = __attribute__((ext_vector_type(8)))  short;  // 8 bf16

#define C_TOT 160
#define PZ_   37
#define NTAP  343
#define NROW  (4 * PZ_ * PZ_)   // 5476 (b,z,y) rows per chunk
#define KSN   8
#define SLICE_E 1048576         // bf16 elems per partial slice (4*64*4096)

// conv LDS: A-stripe rows (1216 B data + 16 pad = 1232 stride), split by
// y'-parity: A_E = 19 rows (y'=0,2,..,36) at [0, 23552); A_O = 18 rows
// (y'=1,3,..,35) at [23552, 46080). B at 46080: [kx7][nt2][cg2][n32][16B],
// double-buffered 2x14336. Total 74752 B (x2 blocks/CU = 149504 <= 160KB).
// Epilogue reuses [0, 33792) as yb[64n][33 f4].
#define AROW    1232
#define AE_ROWS 19
#define AO_ROWS 18
#define AE_SZ   23552            // 23 chunks of 1024 (data 23408)
#define AO_OFF  23552
#define AO_SZ   22528            // 22 chunks (data 22176)
#define B_OFF   46080
#define BSZ     14336
#define LDS_SZ  (B_OFF + 2 * BSZ)   // 74752

__device__ __forceinline__ void gl_lds16(const void* g, void* l) {
    __builtin_amdgcn_global_load_lds(
        (const __attribute__((address_space(1))) unsigned int*)g,
        (__attribute__((address_space(3))) unsigned int*)l, 16, 0, 0);
}

__device__ __forceinline__ void pair_ij(int p, int& i, int& j) {
    if (p < 3)      { i = p; j = p; }
    else if (p == 3){ i = 0; j = 1; }
    else if (p == 4){ i = 0; j = 2; }
    else            { i = 1; j = 2; }
}

struct bf2 { __hip_bfloat16 x, y; };
struct bh4 { __hip_bfloat16 x, y, z, w; };

// ---------------------------------------------------------------------------
// Merged prep: bid < 1372 -> build_w (tap = bid>>2, j-quarter), else build_xt.
// xt[chunk][brow][s][16ch], brow=(b*37+z)*37+y.  wl[chunk][tap][n][16ch].
// ---------------------------------------------------------------------------
__global__ void prep_kernel(
    const float* __restrict__ sv,
    const float* __restrict__ b_ss, const float* __restrict__ w_ss,
    const float* __restrict__ b_sv, const float* __restrict__ w_sv,
    const float* __restrict__ b_st, const float* __restrict__ w_st,
    const float* __restrict__ b_vs, const float* __restrict__ w_vs,
    const float* __restrict__ b_vv, const float* __restrict__ w_vv,
    const float* __restrict__ b_vt, const float* __restrict__ w_vt,
    __hip_bfloat16* __restrict__ xt, __hip_bfloat16* __restrict__ wl)
{
    __shared__ float S[13056];
    const int tid = threadIdx.x;

    if (blockIdx.x < 1372) {
        // ---------------- build_w ----------------
        float* L = S;           // 750
        float* W = S + 768;     // 12288
        const int tap = blockIdx.x >> 2;
        const int jq  = (blockIdx.x & 3) * 10;
        for (int r = tid; r < 750; r += 256) {
            float v;
            if (r < 3)        v = b_ss[r * NTAP + tap];
            else if (r < 12)  v = b_sv[(r - 3) * NTAP + tap];
            else if (r < 93)  v = b_st[(r - 12) * NTAP + tap];
            else if (r < 102) v = b_vs[(r - 93) * NTAP + tap];
            else if (r < 183) v = b_vv[(r - 102) * NTAP + tap];
            else              v = b_vt[(r - 183) * NTAP + tap];
            L[r] = v;
        }
        for (int r = tid; r < 12288; r += 256) {
            float v;
            if (r < 768)       v = w_ss[r];
            else if (r < 1536) v = w_sv[r - 768];
            else if (r < 3840) v = w_st[r - 1536];
            else if (r < 4608) v = w_vs[r - 3840];
            else if (r < 6912) v = w_vv[r - 4608];
            else               v = w_vt[r - 6912];
            W[r] = v;
        }
        __syncthreads();
        for (int j = jq; j < jq + 10; ++j) {
            const int idx = j * 256 + tid;
            const int c = idx % C_TOT, n = idx / C_TOT;
            float acc = 0.f;
            if (n < 16) {
                const int u = n;
                if (c < 16) {
                    for (int t = 0; t < 3; ++t) acc += W[(u*16 + c)*3 + t] * L[t];
                } else if (c < 64) {
                    int mm = (c-16)/3, di = (c-16)%3;
                    for (int t = 0; t < 3; ++t)
                        acc += W[768 + (u*16+mm)*3 + t] * L[3 + t*3 + di];
                } else {
                    int q = c-64, mm = q/6, p = q%6, i, jj;
                    pair_ij(p, i, jj);
                    int d1 = i*3+jj, d2 = jj*3+i;
                    for (int t = 0; t < 9; ++t) {
                        float bs = L[12 + t*9 + d1];
                        if (i != jj) bs += L[12 + t*9 + d2];
                        acc += W[1536 + (u*16+mm)*9 + t] * bs;
                    }
                }
            } else {
                const int u = (n-16)/3, dn = (n-16)%3;
                if (c < 16) {
                    for (int t = 0; t < 3; ++t)
                        acc += W[3840 + (u*16+c)*3 + t] * L[93 + t*3 + dn];
                } else if (c < 64) {
                    int mm = (c-16)/3, di = (c-16)%3;
                    for (int t = 0; t < 9; ++t)
                        acc += W[4608 + (u*16+mm)*9 + t] * L[102 + (t*3+dn)*3 + di];
                } else {
                    int q = c-64, mm = q/6, p = q%6, i, jj;
                    pair_ij(p, i, jj);
                    int d1 = i*3+jj, d2 = jj*3+i;
                    for (int t = 0; t < 21; ++t) {
                        float bs = L[183 + (t*3+dn)*9 + d1];
                        if (i != jj) bs += L[183 + (t*3+dn)*9 + d2];
                        acc += W[6912 + (u*16+mm)*21 + t] * bs;
                    }
                }
            }
            const int chunk = c >> 4, cw = c & 15;
            wl[((size_t)chunk * NTAP + tap) * 1024 + (size_t)n * 16 + cw] =
                __float2bfloat16(acc);
        }
    } else {
        // ---------------- build_xt ----------------
        float* row = S;                              // 32*66 = 2112
        const int bid = blockIdx.x - 1372;           // (b*37 + z)*37 + y
        const int y = bid % 37, z = (bid / 37) % 37, b = bid / 1369;
        const bool interior = (z >= 3 && z < 35 && y >= 3 && y < 35);
        if (interior) {
            const float* src = sv + (size_t)b * 2097152 + (z-3) * 1024 + (y-3) * 32;
            for (int f = tid; f < 2048; f += 256) {
                int ch = f >> 5, x = f & 31;
                row[x * 66 + ch] = src[(size_t)ch * 32768 + x];
            }
        }
        __syncthreads();
        for (int e2 = tid; e2 < 38 * 80; e2 += 256) {
            const int s = e2 / 80, cp = e2 % 80, c = cp * 2;
            float v0 = 0.f, v1 = 0.f;
            if (interior && s >= 3 && s < 35) {
                const int x = s - 3;
                if (c < 64) {
                    v0 = row[x * 66 + c];
                    v1 = row[x * 66 + c + 1];
                } else {
                    int q = c - 64, u = q / 6, p = q % 6, i, j;
                    pair_ij(p, i, j);
                    v0 = row[x * 66 + 16 + u * 3 + i] * row[x * 66 + 16 + u * 3 + j];
                    pair_ij(p + 1, i, j);
                    v1 = row[x * 66 + 16 + u * 3 + i] * row[x * 66 + 16 + u * 3 + j];
                }
            }
            bf2 w{__float2bfloat16(v0), __float2bfloat16(v1)};
            const int chunk = c >> 4, cw = c & 15;
            *(bf2*)(xt + ((size_t)chunk * NROW + bid) * 608 + s * 16 + cw) = w;
        }
    }
}

// ---------------------------------------------------------------------------
// Conv. Grid 64*KSN = 512 (2 blocks/CU). Block = (b, oz single z-out, ks).
// Output tile 64ch x (1z x 16y x 16x). K split by (chunk,kz) groups g =
// ks..69 step 8. Per group: A-stripe = 37 xt rows (contiguous) at z'=2*oz+kz,
// staged once, split even/odd y' halves; taps ordered ky = 1,3,5,0,2,4,6 so
// the idle half is re-staged for the next group during the other phase.
// B staged per tap (dbuf). One barrier per tap.
// ---------------------------------------------------------------------------
__global__ __launch_bounds__(256, 2) void conv_mfma_kernel(
    const __hip_bfloat16* __restrict__ xt,
    const __hip_bfloat16* __restrict__ wl,
    __hip_bfloat16* __restrict__ y4b)
{
    __shared__ __align__(16) char lds[LDS_SZ];

    // T1 XCD swizzle: grid = 512 = 8 XCDs x 64.
    const int phys = blockIdx.x;
    const int bid  = (phys & 7) * (64 * KSN / 8) + (phys >> 3);

    const int low3 = bid & 7;
    const int rest = bid >> 3;
    const int ks   = rest % KSN;
    const int mb   = (rest / KSN) * 8 + low3;   // 0..63
    const int b    = mb >> 4;                   // 0..3
    const int oz   = mb & 15;                   // z-out 0..15

    const int tid  = threadIdx.x;
    const int w    = tid >> 6;          // x-quarter
    const int lane = tid & 63;
    const int m    = lane & 31;
    const int h    = lane >> 5;         // k-half (8-ch group)

    // ---- per-lane invariant staging source offsets (elements) ----
    // A half-stripes staged as linear 1KB chunks into padded-row layout.
    int invAE[6]; int nAE = 0;
#pragma unroll
    for (int k = 0; k < 6; ++k) {
        const int i = w + 4 * k;
        if (i < 23) {
            const int o = i * 1024 + lane * 16;
            int r = o / AROW;
            int rem = o - r * AROW;
            if (r > AE_ROWS - 1) { r = AE_ROWS - 1; rem = 0; }
            if (rem >= 1216) rem = 0;
            const int s  = rem >> 5;
            const int cg = ((rem >> 4) & 1) ^ ((s >> 1) & 1);
            invAE[k] = (2 * r) * 608 + s * 16 + cg * 8;      // y' = 2r
            nAE = k + 1;
        }
    }
    int invAO[6]; int nAO = 0;
#pragma unroll
    for (int k = 0; k < 6; ++k) {
        const int i = w + 4 * k;
        if (i < 22) {
            const int o = i * 1024 + lane * 16;
            int r = o / AROW;
            int rem = o - r * AROW;
            if (r > AO_ROWS - 1) { r = AO_ROWS - 1; rem = 0; }
            if (rem >= 1216) rem = 0;
            const int s  = rem >> 5;
            const int cg = ((rem >> 4) & 1) ^ ((s >> 1) & 1);
            invAO[k] = (2 * r + 1) * 608 + s * 16 + cg * 8;  // y' = 2r+1
            nAO = k + 1;
        }
    }
    int invB[4]; int nB = 0;
#pragma unroll
    for (int k = 0; k < 4; ++k) {
        const int i = w + 4 * k;
        if (i < 14) {
            const int kx = i >> 1, nt = i & 1;
            invB[k] = kx * 1024 + (nt * 32 + m) * 16 + h * 8;
            nB = k + 1;
        }
    }

    f16v acc[2][2];
    for (int t = 0; t < 2; ++t)
        for (int n = 0; n < 2; ++n)
            for (int k = 0; k < 16; ++k) acc[t][n][k] = 0.f;

    const int rA0   = ((m >> 4) << 2) + ((m >> 2) & 3);   // yo base 0..7
    const int sbase = (w << 3) + ((m & 3) << 1);          // + kx -> x slot

    auto stageAE = [&](int g) {
        const int chunk = g / 7, kz = g - chunk * 7;
        const size_t u = ((size_t)chunk * NROW + (size_t)(b * PZ_ + 2 * oz + kz) * PZ_) * 608;
#pragma unroll
        for (int k = 0; k < 6; ++k)
            if (k < nAE) gl_lds16(xt + u + invAE[k], lds + (w + 4 * k) * 1024);
    };
    auto stageAO = [&](int g) {
        const int chunk = g / 7, kz = g - chunk * 7;
        const size_t u = ((size_t)chunk * NROW + (size_t)(b * PZ_ + 2 * oz + kz) * PZ_) * 608;
#pragma unroll
        for (int k = 0; k < 6; ++k)
            if (k < nAO) gl_lds16(xt + u + invAO[k], lds + AO_OFF + (w + 4 * k) * 1024);
    };
    auto stageB = [&](int g, int kyv, int bsel) {
        const int chunk = g / 7, kz = g - chunk * 7;
        const size_t u = ((size_t)chunk * NTAP + (size_t)(kz * 7 + kyv) * 7) * 1024;
        char* dst = lds + B_OFF + bsel * BSZ;
#pragma unroll
        for (int k = 0; k < 4; ++k)
            if (k < nB) gl_lds16(wl + u + invB[k], dst + (w + 4 * k) * 1024);
    };

    auto compute = [&](int ky, int bsel) {
        const int abase = (ky & 1) ? AO_OFF : 0;
        const char* abp = lds + abase + (rA0 + (ky >> 1)) * AROW;
        const char* bbp = lds + B_OFF + bsel * BSZ;
#pragma unroll
        for (int kx = 0; kx < 7; ++kx) {
            const int s   = sbase + kx;
            const int cgp = h ^ ((s >> 1) & 1);
            const char* ap = abp + s * 32 + cgp * 16;
            const s8 a0 = *(const s8*)(ap);
            const s8 a1 = *(const s8*)(ap + 8 * AROW);
            const char* bp = bbp + kx * 2048 + h * 512 + m * 16;
            const s8 b0 = *(const s8*)(bp);
            const s8 b1 = *(const s8*)(bp + 1024);
            acc[0][0] = __builtin_amdgcn_mfma_f32_32x32x16_bf16(a0, b0, acc[0][0], 0, 0, 0);
            acc[0][1] = __builtin_amdgcn_mfma_f32_32x32x16_bf16(a0, b1, acc[0][1], 0, 0, 0);
            acc[1][0] = __builtin_amdgcn_mfma_f32_32x32x16_bf16(a1, b0, acc[1][0], 0, 0, 0);
            acc[1][1] = __builtin_amdgcn_mfma_f32_32x32x16_bf16(a1, b1, acc[1][1], 0, 0, 0);
        }
    };

    // ---- main loop: groups g = ks..69 step 8; taps ky order 1,3,5,0,2,4,6 ----
    const int G = (ks < 6) ? 9 : 8;
    const int T = G * 7;
    stageAO(ks);
    stageB(ks, 1, 0);
    __syncthreads();
    int bB = 0;
    for (int t = 0; t < T; ++t) {
        const int gi = t / 7, p = t - gi * 7;
        const int g  = ks + gi * KSN;
        const int ky = (p < 3) ? (2 * p + 1) : (2 * (p - 3));
        const int tn = t + 1;
        if (tn < T) {
            const int gin = tn / 7, pn = tn - gin * 7;
            const int kyn = (pn < 3) ? (2 * pn + 1) : (2 * (pn - 3));
            stageB(ks + gin * KSN, kyn, bB ^ 1);
        }
        if (p == 0) stageAE(g);                        // compute reads A_O
        else if (p == 3 && g + KSN < 70) stageAO(g + KSN);  // compute reads A_E
        compute(ky, bB);
        __syncthreads();                               // drains lds-DMA
        bB ^= 1;
    }

    // ---- epilogue: two-pass LDS transpose, coalesced bf16 partial stores ----
    // C/D 32x32: col(n)=lane&31, row m32=(reg&3)+8*(reg>>2)+4*h  [m74/m101]
    // spatial: yo = 8t + 4*(rr>>2) + (rr&3), xo = wq*4 + elem.
    const int nl = lane & 31;
    f4* yb = (f4*)lds;                  // [64n][33 f4] padded = 33792 B
    __hip_bfloat16* dst0 = y4b + (size_t)ks * SLICE_E + (size_t)(b * 64) * 4096
                         + (size_t)oz * 256;
#pragma unroll
    for (int t = 0; t < 2; ++t) {       // yo-half
        __syncthreads();                // prior readers (or compute) done
#pragma unroll
        for (int nt = 0; nt < 2; ++nt) {
            const int n = nt * 32 + nl;
#pragma unroll
            for (int q = 0; q < 4; ++q) {
                const int rr = 2 * q + h;
                f4 v = { acc[t][nt][4*q], acc[t][nt][4*q+1],
                         acc[t][nt][4*q+2], acc[t][nt][4*q+3] };
                yb[n * 33 + rr * 4 + w] = v;
            }
        }
        __syncthreads();
        for (int j = tid; j < 2048; j += 256) {
            const int n  = j >> 5, sp = j & 31;    // sp = rr*4 + wq
            f4 v = yb[n * 33 + sp];
            const int rr = sp >> 2, wq = sp & 3;
            const int yo = t * 8 + (rr >> 2) * 4 + (rr & 3);
            bh4 p{__float2bfloat16(v.x), __float2bfloat16(v.y),
                  __float2bfloat16(v.z), __float2bfloat16(v.w)};
            *(bh4*)(dst0 + (size_t)n * 4096 + yo * 16 + wq * 4) = p;
        }
    }
}

// ---------------------------------------------------------------------------
// Combine KSN bf16 partials -> f32 yc + per-(n,b) sum of squares. 256 blocks.
// ---------------------------------------------------------------------------
__global__ void combine_reduce_kernel(const __hip_bfloat16* __restrict__ y4b,
                                      float* __restrict__ yc,
                                      float* __restrict__ sums2)
{
    const int n = blockIdx.x & 63, q = blockIdx.x >> 6;
    const size_t base = ((size_t)q * 64 + n) * 4096;
    float s = 0.f;
    for (int i = threadIdx.x; i < 1024; i += 256) {
        const size_t off = base + (size_t)i * 4;
        f4 v = {0.f, 0.f, 0.f, 0.f};
#pragma unroll
        for (int k = 0; k < KSN; ++k) {
            bh4 r = *(const bh4*)(y4b + off + (size_t)k * SLICE_E);
            v.x += (float)r.x; v.y += (float)r.y;
            v.z += (float)r.z; v.w += (float)r.w;
        }
        *(f4*)(yc + off) = v;
        s += v.x * v.x + v.y * v.y + v.z * v.z + v.w * v.w;
    }
    __shared__ float red[256];
    red[threadIdx.x] = s;
    __syncthreads();
    for (int st = 128; st > 0; st >>= 1) {
        if (threadIdx.x < st) red[threadIdx.x] += red[threadIdx.x + st];
        __syncthreads();
    }
    if (threadIdx.x == 0) sums2[n * 4 + q] = red[0];
}

// ---------------------------------------------------------------------------
__global__ void finalize_kernel(const float* __restrict__ yc,
                                const float* __restrict__ sums2,
                                const float* __restrict__ g_s,
                                const float* __restrict__ g_v,
                                const float* __restrict__ bias_s,
                                float* __restrict__ out)
{
    const int idx = blockIdx.x * 256 + threadIdx.x;   // exact grid, 1M
    const int n = (idx >> 12) & 63;
    float v = yc[idx];
    if (n < 16) {
        float sum = sums2[n*4] + sums2[n*4+1] + sums2[n*4+2] + sums2[n*4+3];
        float var = sum * (1.0f / 16384.0f);
        float sc  = g_s[n] / sqrtf(var + 1e-5f);
        v = fmaxf(v * sc + bias_s[n], 0.f);
    } else {
        int u = (n - 16) / 3;
        float sum = 0.f;
        for (int k = 0; k < 12; ++k) sum += sums2[(16 + u * 3) * 4 + k];
        float var = sum * (1.0f / 49152.0f);
        v = v * (g_v[u] / sqrtf(var + 1e-5f));
    }
    out[idx] = v;
}

// ---------------------------------------------------------------------------
extern "C" void kernel_launch(void* const* d_in, const int* in_sizes, int n_in,
                              void* d_out, int out_size, void* d_ws, size_t ws_size,
                              hipStream_t stream)
{
    const float* sv    = (const float*)d_in[0];
    const float* b_ss  = (const float*)d_in[1];
    const float* w_ss  = (const float*)d_in[2];
    const float* b_sv  = (const float*)d_in[3];
    const float* w_sv  = (const float*)d_in[4];
    const float* b_st  = (const float*)d_in[5];
    const float* w_st  = (const float*)d_in[6];
    const float* b_vs  = (const float*)d_in[7];
    const float* w_vs  = (const float*)d_in[8];
    const float* b_vv  = (const float*)d_in[9];
    const float* w_vv  = (const float*)d_in[10];
    const float* b_vt  = (const float*)d_in[11];
    const float* w_vt  = (const float*)d_in[12];
    const float* bn_gs = (const float*)d_in[13];
    const float* bn_gv = (const float*)d_in[14];
    const float* bias_s= (const float*)d_in[15];
    float* out = (float*)d_out;

    char* ws = (char*)d_ws;
    constexpr size_t XT_BYTES = (size_t)10 * NROW * 1216;      // 66,588,160
    constexpr size_t WL_BYTES = (size_t)10 * NTAP * 2048;      //  7,024,640
    constexpr size_t Y4_BYTES = (size_t)KSN * SLICE_E * 2;     // 16,777,216
    constexpr size_t YC_BYTES = (size_t)4 * 64 * 4096 * 4;     //  4,194,304

    __hip_bfloat16* xt  = (__hip_bfloat16*)ws;
    __hip_bfloat16* wl  = (__hip_bfloat16*)(ws + XT_BYTES);
    __hip_bfloat16* y4b = (__hip_bfloat16*)(ws + XT_BYTES + WL_BYTES);
    float* yc    = (float*)(ws + XT_BYTES + WL_BYTES + Y4_BYTES);
    float* sums2 = (float*)(ws + XT_BYTES + WL_BYTES + Y4_BYTES + YC_BYTES);

    prep_kernel<<<1372 + 5476, 256, 0, stream>>>(
        sv, b_ss, w_ss, b_sv, w_sv, b_st, w_st, b_vs, w_vs, b_vv, w_vv,
        b_vt, w_vt, xt, wl);
    conv_mfma_kernel<<<64 * KSN, 256, 0, stream>>>(xt, wl, y4b);
    combine_reduce_kernel<<<256, 256, 0, stream>>>(y4b, yc, sums2);
    finalize_kernel<<<4096, 256, 0, stream>>>(yc, sums2, bn_gs, bn_gv, bias_s, out);
}

// Round 5
// 272.822 us; speedup vs baseline: 1.0456x; 1.0096x over previous
//
#include <hip/hip_runtime.h>
#include <hip/hip_bf16.h>

// ---------------------------------------------------------------------------
// Equivariant conv block. MFMA 32x32x16 implicit GEMM.
// R13 post-mortem: staged bytes -40% -> dur unchanged => NOT byte-service
// bound. Invariant = LDS reads (1 ds_read_b128 per MFMA; b128=12cyc vs
// mfma=8cyc -> LDS pipe 1.5x oversubscribed; 43.5% of peak matches 8/12
// ceiling minus conflicts). R14: acc[2][2] -> acc[4][2] register tile:
// per kx 6 reads feed 8 MFMAs (0.75 reads/MFMA, B-reads halved). Block now
// covers an oz-PAIR (512 spatial); grid 256 = 1 block/CU; LDS = 2 z'-stripes
// (4 parity half-stripes, 92KB) + B dbuf (28.7KB) = 118KB. Parity ping-pong:
// taps ky=1,3,5,0,2,4,6; AE(g) staged at p=0,1 (first even use p=3);
// AO(g+8) staged at p=3,4 (used next group p=0). Epilogue: 4 passes.
// ---------------------------------------------------------------------------

using f4  = __attribute__((ext_vector_type(4)))  float;
using f16v= __attribute__((ext_vector_type(16))) float;
using s8  = __attribute__((ext_vector_type(8)))  short;  // 8 bf16

#define C_TOT 160
#define PZ_   37
#define NTAP  343
#define NROW  (4 * PZ_ * PZ_)   // 5476 (b,z,y) rows per chunk
#define KSN   8
#define GRID_C 256
#define SLICE_E 1048576         // bf16 elems per partial slice (4*64*4096)

// conv LDS: per z'-stripe: A_E = 19 rows (y'=0,2,..,36) in 23552 B,
// A_O = 18 rows (y'=1,..,35) in 22528 B; stripe block = 46080 B. Two stripes
// (oz-pair) = 92160. B at 92160: [kx7][nt2][cg2][n32][16B] dbuf 2x14336.
// Total 120832 (1 block/CU). Rows padded: 1216 data + 16 = 1232 stride.
// Epilogue reuses [0, 33792) as yb[64n][33 f4].
#define AROW      1232
#define AE_ROWS   19
#define AO_ROWS   18
#define AO_OFF    23552
#define STRIPE_SZ 46080
#define B_OFF     92160
#define BSZ       14336
#define LDS_SZ    (B_OFF + 2 * BSZ)   // 120832

__device__ __forceinline__ void gl_lds16(const void* g, void* l) {
    __builtin_amdgcn_global_load_lds(
        (const __attribute__((address_space(1))) unsigned int*)g,
        (__attribute__((address_space(3))) unsigned int*)l, 16, 0, 0);
}

__device__ __forceinline__ void pair_ij(int p, int& i, int& j) {
    if (p < 3)      { i = p; j = p; }
    else if (p == 3){ i = 0; j = 1; }
    else if (p == 4){ i = 0; j = 2; }
    else            { i = 1; j = 2; }
}

struct bf2 { __hip_bfloat16 x, y; };
struct bh4 { __hip_bfloat16 x, y, z, w; };

// ---------------------------------------------------------------------------
// Merged prep: bid < 1372 -> build_w (tap = bid>>2, j-quarter), else build_xt.
// xt[chunk][brow][s][16ch], brow=(b*37+z)*37+y.  wl[chunk][tap][n][16ch].
// ---------------------------------------------------------------------------
__global__ void prep_kernel(
    const float* __restrict__ sv,
    const float* __restrict__ b_ss, const float* __restrict__ w_ss,
    const float* __restrict__ b_sv, const float* __restrict__ w_sv,
    const float* __restrict__ b_st, const float* __restrict__ w_st,
    const float* __restrict__ b_vs, const float* __restrict__ w_vs,
    const float* __restrict__ b_vv, const float* __restrict__ w_vv,
    const float* __restrict__ b_vt, const float* __restrict__ w_vt,
    __hip_bfloat16* __restrict__ xt, __hip_bfloat16* __restrict__ wl)
{
    __shared__ float S[13056];
    const int tid = threadIdx.x;

    if (blockIdx.x < 1372) {
        // ---------------- build_w ----------------
        float* L = S;           // 750
        float* W = S + 768;     // 12288
        const int tap = blockIdx.x >> 2;
        const int jq  = (blockIdx.x & 3) * 10;
        for (int r = tid; r < 750; r += 256) {
            float v;
            if (r < 3)        v = b_ss[r * NTAP + tap];
            else if (r < 12)  v = b_sv[(r - 3) * NTAP + tap];
            else if (r < 93)  v = b_st[(r - 12) * NTAP + tap];
            else if (r < 102) v = b_vs[(r - 93) * NTAP + tap];
            else if (r < 183) v = b_vv[(r - 102) * NTAP + tap];
            else              v = b_vt[(r - 183) * NTAP + tap];
            L[r] = v;
        }
        for (int r = tid; r < 12288; r += 256) {
            float v;
            if (r < 768)       v = w_ss[r];
            else if (r < 1536) v = w_sv[r - 768];
            else if (r < 3840) v = w_st[r - 1536];
            else if (r < 4608) v = w_vs[r - 3840];
            else if (r < 6912) v = w_vv[r - 4608];
            else               v = w_vt[r - 6912];
            W[r] = v;
        }
        __syncthreads();
        for (int j = jq; j < jq + 10; ++j) {
            const int idx = j * 256 + tid;
            const int c = idx % C_TOT, n = idx / C_TOT;
            float acc = 0.f;
            if (n < 16) {
                const int u = n;
                if (c < 16) {
                    for (int t = 0; t < 3; ++t) acc += W[(u*16 + c)*3 + t] * L[t];
                } else if (c < 64) {
                    int mm = (c-16)/3, di = (c-16)%3;
                    for (int t = 0; t < 3; ++t)
                        acc += W[768 + (u*16+mm)*3 + t] * L[3 + t*3 + di];
                } else {
                    int q = c-64, mm = q/6, p = q%6, i, jj;
                    pair_ij(p, i, jj);
                    int d1 = i*3+jj, d2 = jj*3+i;
                    for (int t = 0; t < 9; ++t) {
                        float bs = L[12 + t*9 + d1];
                        if (i != jj) bs += L[12 + t*9 + d2];
                        acc += W[1536 + (u*16+mm)*9 + t] * bs;
                    }
                }
            } else {
                const int u = (n-16)/3, dn = (n-16)%3;
                if (c < 16) {
                    for (int t = 0; t < 3; ++t)
                        acc += W[3840 + (u*16+c)*3 + t] * L[93 + t*3 + dn];
                } else if (c < 64) {
                    int mm = (c-16)/3, di = (c-16)%3;
                    for (int t = 0; t < 9; ++t)
                        acc += W[4608 + (u*16+mm)*9 + t] * L[102 + (t*3+dn)*3 + di];
                } else {
                    int q = c-64, mm = q/6, p = q%6, i, jj;
                    pair_ij(p, i, jj);
                    int d1 = i*3+jj, d2 = jj*3+i;
                    for (int t = 0; t < 21; ++t) {
                        float bs = L[183 + (t*3+dn)*9 + d1];
                        if (i != jj) bs += L[183 + (t*3+dn)*9 + d2];
                        acc += W[6912 + (u*16+mm)*21 + t] * bs;
                    }
                }
            }
            const int chunk = c >> 4, cw = c & 15;
            wl[((size_t)chunk * NTAP + tap) * 1024 + (size_t)n * 16 + cw] =
                __float2bfloat16(acc);
        }
    } else {
        // ---------------- build_xt ----------------
        float* row = S;                              // 32*66 = 2112
        const int bid = blockIdx.x - 1372;           // (b*37 + z)*37 + y
        const int y = bid % 37, z = (bid / 37) % 37, b = bid / 1369;
        const bool interior = (z >= 3 && z < 35 && y >= 3 && y < 35);
        if (interior) {
            const float* src = sv + (size_t)b * 2097152 + (z-3) * 1024 + (y-3) * 32;
            for (int f = tid; f < 2048; f += 256) {
                int ch = f >> 5, x = f & 31;
                row[x * 66 + ch] = src[(size_t)ch * 32768 + x];
            }
        }
        __syncthreads();
        for (int e2 = tid; e2 < 38 * 80; e2 += 256) {
            const int s = e2 / 80, cp = e2 % 80, c = cp * 2;
            float v0 = 0.f, v1 = 0.f;
            if (interior && s >= 3 && s < 35) {
                const int x = s - 3;
                if (c < 64) {
                    v0 = row[x * 66 + c];
                    v1 = row[x * 66 + c + 1];
                } else {
                    int q = c - 64, u = q / 6, p = q % 6, i, j;
                    pair_ij(p, i, j);
                    v0 = row[x * 66 + 16 + u * 3 + i] * row[x * 66 + 16 + u * 3 + j];
                    pair_ij(p + 1, i, j);
                    v1 = row[x * 66 + 16 + u * 3 + i] * row[x * 66 + 16 + u * 3 + j];
                }
            }
            bf2 w{__float2bfloat16(v0), __float2bfloat16(v1)};
            const int chunk = c >> 4, cw = c & 15;
            *(bf2*)(xt + ((size_t)chunk * NROW + bid) * 608 + s * 16 + cw) = w;
        }
    }
}

// ---------------------------------------------------------------------------
// Conv. Grid 256 (1 block/CU). Block = (b, ozp oz-pair, ks). Output tile
// 64ch x (2z x 16y x 16x). Wave = acc[4][2]: 128 m (2 oz x 8 yo-half rows
// pattern) x 64 n. Per kx: 4 A reads + 2 B reads -> 8 MFMAs (0.75 rd/MFMA).
// K groups g=(chunk,kz) = ks..69 step 8; per group both z'-stripes staged
// once via even/odd parity ping-pong. One barrier per tap.
// ---------------------------------------------------------------------------
__global__ __launch_bounds__(256, 1) void conv_mfma_kernel(
    const __hip_bfloat16* __restrict__ xt,
    const __hip_bfloat16* __restrict__ wl,
    __hip_bfloat16* __restrict__ y4b)
{
    __shared__ __align__(16) char lds[LDS_SZ];

    // T1 XCD swizzle: grid = 256 = 8 XCDs x 32.
    const int phys = blockIdx.x;
    const int bid  = (phys & 7) * (GRID_C / 8) + (phys >> 3);

    const int low3 = bid & 7;
    const int rest = bid >> 3;
    const int ks   = rest % KSN;
    const int mb   = (rest / KSN) * 8 + low3;   // 0..31
    const int b    = mb >> 3;                   // 0..3
    const int ozp  = mb & 7;                    // oz pair: oz = 2*ozp + zi

    const int tid  = threadIdx.x;
    const int w    = tid >> 6;          // x-quarter
    const int lane = tid & 63;
    const int m    = lane & 31;
    const int h    = lane >> 5;         // k-half (8-ch group)

    // ---- per-lane invariant staging source offsets (elements) ----
    int invAE[6]; int nAE = 0;
#pragma unroll
    for (int k = 0; k < 6; ++k) {
        const int i = w + 4 * k;
        if (i < 23) {
            const int o = i * 1024 + lane * 16;
            int r = o / AROW;
            int rem = o - r * AROW;
            if (r > AE_ROWS - 1) { r = AE_ROWS - 1; rem = 0; }
            if (rem >= 1216) rem = 0;
            const int s  = rem >> 5;
            const int cg = ((rem >> 4) & 1) ^ ((s >> 1) & 1);
            invAE[k] = (2 * r) * 608 + s * 16 + cg * 8;      // y' = 2r
            nAE = k + 1;
        }
    }
    int invAO[6]; int nAO = 0;
#pragma unroll
    for (int k = 0; k < 6; ++k) {
        const int i = w + 4 * k;
        if (i < 22) {
            const int o = i * 1024 + lane * 16;
            int r = o / AROW;
            int rem = o - r * AROW;
            if (r > AO_ROWS - 1) { r = AO_ROWS - 1; rem = 0; }
            if (rem >= 1216) rem = 0;
            const int s  = rem >> 5;
            const int cg = ((rem >> 4) & 1) ^ ((s >> 1) & 1);
            invAO[k] = (2 * r + 1) * 608 + s * 16 + cg * 8;  // y' = 2r+1
            nAO = k + 1;
        }
    }
    int invB[4]; int nB = 0;
#pragma unroll
    for (int k = 0; k < 4; ++k) {
        const int i = w + 4 * k;
        if (i < 14) {
            const int kx = i >> 1, nt = i & 1;
            invB[k] = kx * 1024 + (nt * 32 + m) * 16 + h * 8;
            nB = k + 1;
        }
    }

    f16v acc[4][2];
#pragma unroll
    for (int t = 0; t < 4; ++t)
#pragma unroll
        for (int n = 0; n < 2; ++n)
            for (int k = 0; k < 16; ++k) acc[t][n][k] = 0.f;

    const int rA0   = ((m >> 4) << 2) + ((m >> 2) & 3);   // yo base 0..7
    const int sbase = (w << 3) + ((m & 3) << 1);          // + kx -> x slot

    auto stageAE = [&](int g, int st) {
        const int chunk = g / 7, kz = g - chunk * 7;
        const size_t u = ((size_t)chunk * NROW
                        + (size_t)(b * PZ_ + 4 * ozp + 2 * st + kz) * PZ_) * 608;
        char* base = lds + st * STRIPE_SZ;
#pragma unroll
        for (int k = 0; k < 6; ++k)
            if (k < nAE) gl_lds16(xt + u + invAE[k], base + (w + 4 * k) * 1024);
    };
    auto stageAO = [&](int g, int st) {
        const int chunk = g / 7, kz = g - chunk * 7;
        const size_t u = ((size_t)chunk * NROW
                        + (size_t)(b * PZ_ + 4 * ozp + 2 * st + kz) * PZ_) * 608;
        char* base = lds + st * STRIPE_SZ + AO_OFF;
#pragma unroll
        for (int k = 0; k < 6; ++k)
            if (k < nAO) gl_lds16(xt + u + invAO[k], base + (w + 4 * k) * 1024);
    };
    auto stageB = [&](int g, int kyv, int bsel) {
        const int chunk = g / 7, kz = g - chunk * 7;
        const size_t u = ((size_t)chunk * NTAP + (size_t)(kz * 7 + kyv) * 7) * 1024;
        char* dst = lds + B_OFF + bsel * BSZ;
#pragma unroll
        for (int k = 0; k < 4; ++k)
            if (k < nB) gl_lds16(wl + u + invB[k], dst + (w + 4 * k) * 1024);
    };

    auto compute = [&](int ky, int bsel) {
        const int pb = (ky & 1) ? AO_OFF : 0;
        const char* abp = lds + pb + (rA0 + (ky >> 1)) * AROW;
        const char* bbp = lds + B_OFF + bsel * BSZ;
#pragma unroll
        for (int kx = 0; kx < 7; ++kx) {
            const int s   = sbase + kx;
            const int cgp = h ^ ((s >> 1) & 1);
            const char* ap = abp + s * 32 + cgp * 16;
            const s8 a0 = *(const s8*)(ap);
            const s8 a1 = *(const s8*)(ap + 8 * AROW);
            const s8 a2 = *(const s8*)(ap + STRIPE_SZ);
            const s8 a3 = *(const s8*)(ap + STRIPE_SZ + 8 * AROW);
            const char* bp = bbp + kx * 2048 + h * 512 + m * 16;
            const s8 b0 = *(const s8*)(bp);
            const s8 b1 = *(const s8*)(bp + 1024);
            acc[0][0] = __builtin_amdgcn_mfma_f32_32x32x16_bf16(a0, b0, acc[0][0], 0, 0, 0);
            acc[0][1] = __builtin_amdgcn_mfma_f32_32x32x16_bf16(a0, b1, acc[0][1], 0, 0, 0);
            acc[1][0] = __builtin_amdgcn_mfma_f32_32x32x16_bf16(a1, b0, acc[1][0], 0, 0, 0);
            acc[1][1] = __builtin_amdgcn_mfma_f32_32x32x16_bf16(a1, b1, acc[1][1], 0, 0, 0);
            acc[2][0] = __builtin_amdgcn_mfma_f32_32x32x16_bf16(a2, b0, acc[2][0], 0, 0, 0);
            acc[2][1] = __builtin_amdgcn_mfma_f32_32x32x16_bf16(a2, b1, acc[2][1], 0, 0, 0);
            acc[3][0] = __builtin_amdgcn_mfma_f32_32x32x16_bf16(a3, b0, acc[3][0], 0, 0, 0);
            acc[3][1] = __builtin_amdgcn_mfma_f32_32x32x16_bf16(a3, b1, acc[3][1], 0, 0, 0);
        }
    };

    // ---- main loop: groups g = ks..69 step 8; taps ky order 1,3,5,0,2,4,6 ----
    const int G = (70 - ks + KSN - 1) / KSN;   // ks 0..5 -> 9, 6..7 -> 8
    const int T = G * 7;
    stageAO(ks, 0);
    stageAO(ks, 1);
    stageB(ks, 1, 0);
    __syncthreads();
    int bB = 0;
    for (int t = 0; t < T; ++t) {
        const int gi = t / 7, p = t - gi * 7;
        const int g  = ks + gi * KSN;
        const int ky = (p < 3) ? (2 * p + 1) : (2 * (p - 3));
        const int tn = t + 1;
        if (tn < T) {
            const int gin = tn / 7, pn = tn - gin * 7;
            const int kyn = (pn < 3) ? (2 * pn + 1) : (2 * (pn - 3));
            stageB(ks + gin * KSN, kyn, bB ^ 1);
        }
        if      (p == 0) stageAE(g, 0);
        else if (p == 1) stageAE(g, 1);
        else if (p == 3 && g + KSN < 70) stageAO(g + KSN, 0);
        else if (p == 4 && g + KSN < 70) stageAO(g + KSN, 1);
        compute(ky, bB);
        __syncthreads();                               // drains lds-DMA
        bB ^= 1;
    }

    // ---- epilogue: 4-pass LDS transpose, coalesced bf16 partial stores ----
    // C/D 32x32: col(n)=lane&31, row m32=(reg&3)+8*(reg>>2)+4*h  [m74/m101]
    // m32 decode: xo_low2 = reg&3 (j), yo = tt*8 + 4*(rr>>2) + (rr&3).
    const int nl = lane & 31;
    f4* yb = (f4*)lds;                  // [64n][33 f4] padded = 33792 B
    __hip_bfloat16* dst0 = y4b + (size_t)ks * SLICE_E + (size_t)(b * 64) * 4096
                         + (size_t)(2 * ozp) * 256;
#pragma unroll
    for (int e = 0; e < 4; ++e) {       // e = zi*2 + tt
        const int zi = e >> 1, tt = e & 1;
        __syncthreads();                // prior readers (or compute) done
#pragma unroll
        for (int nt = 0; nt < 2; ++nt) {
            const int n = nt * 32 + nl;
#pragma unroll
            for (int q = 0; q < 4; ++q) {
                const int rr = 2 * q + h;
                f4 v = { acc[e][nt][4*q], acc[e][nt][4*q+1],
                         acc[e][nt][4*q+2], acc[e][nt][4*q+3] };
                yb[n * 33 + rr * 4 + w] = v;
            }
        }
        __syncthreads();
        for (int j = tid; j < 2048; j += 256) {
            const int n  = j >> 5, sp = j & 31;    // sp = rr*4 + wq
            f4 v = yb[n * 33 + sp];
            const int rr = sp >> 2, wq = sp & 3;
            const int yo = tt * 8 + (rr >> 2) * 4 + (rr & 3);
            bh4 p{__float2bfloat16(v.x), __float2bfloat16(v.y),
                  __float2bfloat16(v.z), __float2bfloat16(v.w)};
            *(bh4*)(dst0 + (size_t)n * 4096 + zi * 256 + yo * 16 + wq * 4) = p;
        }
    }
}

// ---------------------------------------------------------------------------
// Combine KSN bf16 partials -> f32 yc + per-(n,b) sum of squares. 256 blocks.
// ---------------------------------------------------------------------------
__global__ void combine_reduce_kernel(const __hip_bfloat16* __restrict__ y4b,
                                      float* __restrict__ yc,
                                      float* __restrict__ sums2)
{
    const int n = blockIdx.x & 63, q = blockIdx.x >> 6;
    const size_t base = ((size_t)q * 64 + n) * 4096;
    float s = 0.f;
    for (int i = threadIdx.x; i < 1024; i += 256) {
        const size_t off = base + (size_t)i * 4;
        f4 v = {0.f, 0.f, 0.f, 0.f};
#pragma unroll
        for (int k = 0; k < KSN; ++k) {
            bh4 r = *(const bh4*)(y4b + off + (size_t)k * SLICE_E);
            v.x += (float)r.x; v.y += (float)r.y;
            v.z += (float)r.z; v.w += (float)r.w;
        }
        *(f4*)(yc + off) = v;
        s += v.x * v.x + v.y * v.y + v.z * v.z + v.w * v.w;
    }
    __shared__ float red[256];
    red[threadIdx.x] = s;
    __syncthreads();
    for (int st = 128; st > 0; st >>= 1) {
        if (threadIdx.x < st) red[threadIdx.x] += red[threadIdx.x + st];
        __syncthreads();
    }
    if (threadIdx.x == 0) sums2[n * 4 + q] = red[0];
}

// ---------------------------------------------------------------------------
__global__ void finalize_kernel(const float* __restrict__ yc,
                                const float* __restrict__ sums2,
                                const float* __restrict__ g_s,
                                const float* __restrict__ g_v,
                                const float* __restrict__ bias_s,
                                float* __restrict__ out)
{
    const int idx = blockIdx.x * 256 + threadIdx.x;   // exact grid, 1M
    const int n = (idx >> 12) & 63;
    float v = yc[idx];
    if (n < 16) {
        float sum = sums2[n*4] + sums2[n*4+1] + sums2[n*4+2] + sums2[n*4+3];
        float var = sum * (1.0f / 16384.0f);
        float sc  = g_s[n] / sqrtf(var + 1e-5f);
        v = fmaxf(v * sc + bias_s[n], 0.f);
    } else {
        int u = (n - 16) / 3;
        float sum = 0.f;
        for (int k = 0; k < 12; ++k) sum += sums2[(16 + u * 3) * 4 + k];
        float var = sum * (1.0f / 49152.0f);
        v = v * (g_v[u] / sqrtf(var + 1e-5f));
    }
    out[idx] = v;
}

// ---------------------------------------------------------------------------
extern "C" void kernel_launch(void* const* d_in, const int* in_sizes, int n_in,
                              void* d_out, int out_size, void* d_ws, size_t ws_size,
                              hipStream_t stream)
{
    const float* sv    = (const float*)d_in[0];
    const float* b_ss  = (const float*)d_in[1];
    const float* w_ss  = (const float*)d_in[2];
    const float* b_sv  = (const float*)d_in[3];
    const float* w_sv  = (const float*)d_in[4];
    const float* b_st  = (const float*)d_in[5];
    const float* w_st  = (const float*)d_in[6];
    const float* b_vs  = (const float*)d_in[7];
    const float* w_vs  = (const float*)d_in[8];
    const float* b_vv  = (const float*)d_in[9];
    const float* w_vv  = (const float*)d_in[10];
    const float* b_vt  = (const float*)d_in[11];
    const float* w_vt  = (const float*)d_in[12];
    const float* bn_gs = (const float*)d_in[13];
    const float* bn_gv = (const float*)d_in[14];
    const float* bias_s= (const float*)d_in[15];
    float* out = (float*)d_out;

    char* ws = (char*)d_ws;
    constexpr size_t XT_BYTES = (size_t)10 * NROW * 1216;      // 66,588,160
    constexpr size_t WL_BYTES = (size_t)10 * NTAP * 2048;      //  7,024,640
    constexpr size_t Y4_BYTES = (size_t)KSN * SLICE_E * 2;     // 16,777,216
    constexpr size_t YC_BYTES = (size_t)4 * 64 * 4096 * 4;     //  4,194,304

    __hip_bfloat16* xt  = (__hip_bfloat16*)ws;
    __hip_bfloat16* wl  = (__hip_bfloat16*)(ws + XT_BYTES);
    __hip_bfloat16* y4b = (__hip_bfloat16*)(ws + XT_BYTES + WL_BYTES);
    float* yc    = (float*)(ws + XT_BYTES + WL_BYTES + Y4_BYTES);
    float* sums2 = (float*)(ws + XT_BYTES + WL_BYTES + Y4_BYTES + YC_BYTES);

    prep_kernel<<<1372 + 5476, 256, 0, stream>>>(
        sv, b_ss, w_ss, b_sv, w_sv, b_st, w_st, b_vs, w_vs, b_vv, w_vv,
        b_vt, w_vt, xt, wl);
    conv_mfma_kernel<<<GRID_C, 256, 0, stream>>>(xt, wl, y4b);
    combine_reduce_kernel<<<256, 256, 0, stream>>>(y4b, yc, sums2);
    finalize_kernel<<<4096, 256, 0, stream>>>(yc, sums2, bn_gs, bn_gv, bias_s, out);
}